// Round 8
// baseline (422.721 us; speedup 1.0000x reference)
//
#include <hip/hip_runtime.h>
#include <hip/hip_bf16.h>

#define B_ 4096
#define T_ 128
#define F_ 64
#define H_ 32
#define G_ 128  // 4*H

using short8 = __attribute__((ext_vector_type(8))) short;
using f32x4  = __attribute__((ext_vector_type(4))) float;
using uint4v = __attribute__((ext_vector_type(4))) unsigned int;

#define MFMA16(Af, Bf, Cf) __builtin_amdgcn_mfma_f32_16x16x32_bf16((Af), (Bf), (Cf), 0, 0, 0)

__device__ __forceinline__ float sigmoid_f(float z) {
    return __builtin_amdgcn_rcpf(1.0f + __expf(-z));
}
__device__ __forceinline__ unsigned short bfb(float f) {
    return __builtin_bit_cast(unsigned short, __float2bfloat16(f));
}
__device__ __forceinline__ unsigned int pk(float a, float b) {
    return (unsigned int)bfb(a) | ((unsigned int)bfb(b) << 16);
}

// 4-WAY SPLIT over the transposed recurrence (p-map mechanics validated rounds 6-7).
//   lane = 16*g + c: c = batch col, rows = gate/hidden. 4 waves per 16-row batch tile.
// All waves compute the FULL z redundantly (MFMA issue is cheap at 1 wave/SIMD);
// wave w applies the nonlinearity only to accumulator row r = w:
//   hidden j = 16*jh + 4*g + w  (jh = 0,1) -> 2 h-values per lane per step.
// h-exchange layout: h[j] stored at short-index s(j) = (j&15)*2 + (j>>4); lane's pair
//   (j, j+16) is one dword at dword-index c*20 + 4g + w (stride 20 keeps b128 reads
//   16B-aligned and banks 2-way max). One barrier; read back b128 = 8 bf16 with
//   k-map p2(g,i) = 4g + (i>>1) + 16*(i&1) — applied to BOTH operand sides, so the
//   HW k-permutation cancels (same mechanism as validated p-map).
// Out-proj: wave w handles feature tile m = w (hfrag as A-frag, Wout B-frag via p2).
#define GATES(R)                                              \
    {                                                         \
        float iv0 = sigmoid_f(acc[0][R]);                     \
        float fv0 = sigmoid_f(acc[2][R]);                     \
        float gv0 = fmaxf(acc[4][R], 0.f);                    \
        float ov0 = sigmoid_f(acc[6][R]);                     \
        float cc0 = fmaf(fv0, cs0, iv0 * gv0);                \
        cs0 = cc0;                                            \
        float h0 = ov0 * fmaxf(cc0, 0.f);                     \
        float iv1 = sigmoid_f(acc[1][R]);                     \
        float fv1 = sigmoid_f(acc[3][R]);                     \
        float gv1 = fmaxf(acc[5][R], 0.f);                    \
        float ov1 = sigmoid_f(acc[7][R]);                     \
        float cc1 = fmaf(fv1, cs1, iv1 * gv1);                \
        cs1 = cc1;                                            \
        float h1 = ov1 * fmaxf(cc1, 0.f);                     \
        hword = pk(h0, h1);                                   \
    }

extern "C" __global__ __launch_bounds__(256, 1)
void lstm_ae(const float* __restrict__ x,
             const float* __restrict__ We,
             const float* __restrict__ Ue,
             const float* __restrict__ be,
             const float* __restrict__ Wd,
             const float* __restrict__ Ud,
             const float* __restrict__ bd,
             const float* __restrict__ Wout,
             const float* __restrict__ bout,
             float* __restrict__ out)
{
    const int lane = threadIdx.x & 63;
    const int w    = threadIdx.x >> 6;     // wave id 0..3 (one per SIMD)
    const int g    = lane >> 4;
    const int c    = lane & 15;
    const int b0   = blockIdx.x << 4;

    // h-exchange: [buf][c*20 + dword idx 0..15], stride 20 dwords (16B-aligned b128 reads)
    __shared__ __align__(16) unsigned int hx[2][16 * 20];

    // -------- full encoder weights in every wave (redundant z-compute) --------
    short8 weF[8][2];   // We^T: K=64 -> 2 chunks, natural k-map 8g+i
    short8 ueF[8];      // Ue^T: K=32, p2-map
    f32x4  beC[8];
#pragma unroll
    for (int n = 0; n < 8; ++n) {
#pragma unroll
        for (int kc = 0; kc < 2; ++kc)
#pragma unroll
            for (int i = 0; i < 8; ++i)
                weF[n][kc][i] = (short)bfb(We[(kc * 32 + 8 * g + i) * G_ + 16 * n + c]);
#pragma unroll
        for (int i = 0; i < 8; ++i)
            ueF[n][i] = (short)bfb(Ue[(4 * g + (i >> 1) + 16 * (i & 1)) * G_ + 16 * n + c]);
        beC[n] = *(const f32x4*)(be + 16 * n + 4 * g);
    }

    const float* xr = x + (size_t)(b0 + c) * (T_ * F_);
    const int xo = 8 * g;

    short8 hfrag = (short8)0;   // full h B-frag (k-map p2)
    float cs0 = 0.f, cs1 = 0.f; // cell state for hidden j = 4g+w (jh=0), 16+4g+w (jh=1)

    f32x4 xa = *(const f32x4*)(xr + xo);
    f32x4 xb = *(const f32x4*)(xr + xo + 4);
    f32x4 xc = *(const f32x4*)(xr + 32 + xo);
    f32x4 xd = *(const f32x4*)(xr + 36 + xo);

    // =============================== encoder scan ===============================
#pragma unroll 1
    for (int t = 0; t < T_; ++t) {
        short8 xf0, xf1;
#pragma unroll
        for (int i = 0; i < 4; ++i) {
            xf0[i]     = (short)bfb(xa[i]);
            xf0[4 + i] = (short)bfb(xb[i]);
            xf1[i]     = (short)bfb(xc[i]);
            xf1[4 + i] = (short)bfb(xd[i]);
        }
        if (t + 1 < T_) {
            const float* xn = xr + (t + 1) * F_;
            xa = *(const f32x4*)(xn + xo);
            xb = *(const f32x4*)(xn + xo + 4);
            xc = *(const f32x4*)(xn + 32 + xo);
            xd = *(const f32x4*)(xn + 36 + xo);
        }

        // full z (redundant per wave): x-part first, h-part last (shortest h-chain)
        f32x4 acc[8];
#pragma unroll
        for (int n = 0; n < 8; ++n) {
            acc[n] = MFMA16(weF[n][0], xf0, beC[n]);
            acc[n] = MFMA16(weF[n][1], xf1, acc[n]);
            acc[n] = MFMA16(ueF[n], hfrag, acc[n]);
        }

        unsigned int hword;
        switch (w) {   // wave-uniform branch; static vector index (rule #20)
            case 0: GATES(0) break;
            case 1: GATES(1) break;
            case 2: GATES(2) break;
            default: GATES(3) break;
        }
        hx[t & 1][c * 20 + 4 * g + w] = hword;
        __syncthreads();
        hfrag = __builtin_bit_cast(short8, *(const uint4v*)&hx[t & 1][c * 20 + 4 * g]);
    }

    // ============ decoder weights + constant input zd = bd + Wd^T hT ============
    short8 udF[8];
    f32x4  zd[8];
    {
        short8 wdF[8];
#pragma unroll
        for (int n = 0; n < 8; ++n)
#pragma unroll
            for (int i = 0; i < 8; ++i) {
                const int pr = 4 * g + (i >> 1) + 16 * (i & 1);
                wdF[n][i] = (short)bfb(Wd[pr * G_ + 16 * n + c]);
                udF[n][i] = (short)bfb(Ud[pr * G_ + 16 * n + c]);
            }
#pragma unroll
        for (int n = 0; n < 8; ++n) {
            f32x4 tb = *(const f32x4*)(bd + 16 * n + 4 * g);
            zd[n] = MFMA16(wdF[n], hfrag, tb);   // hfrag == full hT here
        }
    }
    // out-proj weights: this wave's feature tile m = w only
    short8 woF;
    f32x4  boC;
    {
#pragma unroll
        for (int i = 0; i < 8; ++i)
            woF[i] = (short)bfb(Wout[(4 * g + (i >> 1) + 16 * (i & 1)) * F_ + 16 * w + c]);
        float v = bout[16 * w + c];
        boC[0] = v; boC[1] = v; boC[2] = v; boC[3] = v;
    }

    // reset recurrent state
    hfrag = (short8)0;
    cs0 = 0.f; cs1 = 0.f;

    float* ob[4];
#pragma unroll
    for (int r = 0; r < 4; ++r)
        ob[r] = out + (size_t)(b0 + 4 * g + r) * (T_ * F_) + 16 * w + c;

    // ==================== decoder scan + fused output projection ====================
#pragma unroll 1
    for (int t = 0; t < T_; ++t) {
        f32x4 acc[8];
#pragma unroll
        for (int n = 0; n < 8; ++n)
            acc[n] = MFMA16(udF[n], hfrag, zd[n]);   // z = zd + Ud^T h (full, redundant)

        unsigned int hword;
        switch (w) {
            case 0: GATES(0) break;
            case 1: GATES(1) break;
            case 2: GATES(2) break;
            default: GATES(3) break;
        }
        hx[t & 1][c * 20 + 4 * g + w] = hword;
        __syncthreads();
        hfrag = __builtin_bit_cast(short8, *(const uint4v*)&hx[t & 1][c * 20 + 4 * g]);

        // out[b, t, 16w..16w+15]: hfrag as A-frag x Wout B-frag (p2) — tile m = w
        f32x4 oac = MFMA16(hfrag, woF, boC);
#pragma unroll
        for (int r = 0; r < 4; ++r)
            ob[r][t * F_] = oac[r];
    }
}

extern "C" void kernel_launch(void* const* d_in, const int* in_sizes, int n_in,
                              void* d_out, int out_size, void* d_ws, size_t ws_size,
                              hipStream_t stream) {
    (void)in_sizes; (void)n_in; (void)d_ws; (void)ws_size; (void)out_size;
    const float* x    = (const float*)d_in[0];
    const float* We   = (const float*)d_in[1];
    const float* Ue   = (const float*)d_in[2];
    const float* be   = (const float*)d_in[3];
    const float* Wd   = (const float*)d_in[4];
    const float* Ud   = (const float*)d_in[5];
    const float* bd   = (const float*)d_in[6];
    const float* Wout = (const float*)d_in[7];
    const float* bout = (const float*)d_in[8];
    float* out = (float*)d_out;

    dim3 grid(B_ / 16), block(256);
    hipLaunchKernelGGL(lstm_ae, grid, block, 0, stream,
                       x, We, Ue, be, Wd, Ud, bd, Wout, bout, out);
}

// Round 11
// 365.485 us; speedup vs baseline: 1.1566x; 1.1566x over previous
//
#include <hip/hip_runtime.h>
#include <hip/hip_bf16.h>

#define B_ 4096
#define T_ 128
#define F_ 64
#define H_ 32
#define G_ 128  // 4*H

using short8 = __attribute__((ext_vector_type(8))) short;
using f32x4  = __attribute__((ext_vector_type(4))) float;
using uint2v = __attribute__((ext_vector_type(2))) unsigned int;
using uint4v = __attribute__((ext_vector_type(4))) unsigned int;

#define MFMA16(Af, Bf, Cf) __builtin_amdgcn_mfma_f32_16x16x32_bf16((Af), (Bf), (Cf), 0, 0, 0)

__device__ __forceinline__ float sigmoid_f(float z) {
    return __builtin_amdgcn_rcpf(1.0f + __expf(-z));
}
__device__ __forceinline__ unsigned short bfb(float f) {
    return __builtin_bit_cast(unsigned short, __float2bfloat16(f));
}
__device__ __forceinline__ unsigned int pk(float a, float b) {
    return (unsigned int)bfb(a) | ((unsigned int)bfb(b) << 16);
}

// PRODUCER/CONSUMER over the transposed recurrence (p-map validated r6-r8).
//   lane = 16*g + c: c = batch col, rows = gate/hidden. p(g,i) = 4g+(i&3)+16*(i>>2).
// Waves 0,1 (consumers, rw=w): recurrence only — tiles n = 2q+rw, per step:
//   acc[q] = MFMA(ueF[q], hfrag, zxC[q])  (ONE h-dependent MFMA per tile; C = zx from LDS)
//   -> 12 sigmoids -> b64 exchange (identical to round 7).
// Waves 2,3 (helpers, rw=w-2): everything h-independent —
//   encoder: zx[t+1] = be + x[t+1]@We for tiles n = 2q+rw, written to zxbuf[(t+1)&1]
//            (consumed by consumer rw after next barrier; double-buffered, barrier-ordered)
//   decoder: out-proj of h_t (read from hx after the step-t barrier; consumer only
//            overwrites that hx parity after the NEXT barrier -> race-free by ordering).
// Arithmetic is bit-identical to round 7 (same MFMA C-chaining order) -> absmax must match.
extern "C" __global__ __launch_bounds__(256, 1)
void lstm_ae(const float* __restrict__ x,
             const float* __restrict__ We,
             const float* __restrict__ Ue,
             const float* __restrict__ be,
             const float* __restrict__ Wd,
             const float* __restrict__ Ud,
             const float* __restrict__ bd,
             const float* __restrict__ Wout,
             const float* __restrict__ bout,
             float* __restrict__ out)
{
    const int  lane = threadIdx.x & 63;
    const int  w    = threadIdx.x >> 6;
    const bool con  = (w < 2);       // consumer waves 0,1; helper waves 2,3
    const int  rw   = w & 1;         // sub-index within role
    const int  g    = lane >> 4;
    const int  c    = lane & 15;
    const int  b0   = blockIdx.x << 4;

    // h exchange (round-7 layout): [buf][c*18 + 8*wave + 2*g], stride 18 dwords
    __shared__ __align__(16) unsigned int hx[2][16 * 18];
    // zx hand-off: [buf][tile n][lane] f32x4 (canonical b128-per-lane pattern)
    __shared__ __align__(16) f32x4 zxbuf[2][8][64];

    short8 ueF[4];       // consumer: Ue^T (p-map)
    short8 weF[4][2];    // helper: We^T (natural 8g+i k-map, K=64)
    f32x4  beC[4];       // helper: bias rows
    short8 hfrag = (short8)0;
    float  cs[4] = {0.f, 0.f, 0.f, 0.f};
    f32x4  zxC[4];       // consumer: C-operands for current step
    f32x4  xa, xb, xc, xd;  // helper: x staging

    const float* xr = x + (size_t)(b0 + c) * (T_ * F_);
    const int xo = 8 * g;

#define CVTX(xf0, xf1)                                   \
    {                                                    \
        _Pragma("unroll")                                \
        for (int i = 0; i < 4; ++i) {                    \
            xf0[i]     = (short)bfb(xa[i]);              \
            xf0[4 + i] = (short)bfb(xb[i]);              \
            xf1[i]     = (short)bfb(xc[i]);              \
            xf1[4 + i] = (short)bfb(xd[i]);              \
        }                                                \
    }

#define GATES4(ACC, OWN)                                 \
    {                                                    \
        float hv[4];                                     \
        _Pragma("unroll")                                \
        for (int r = 0; r < 4; ++r) {                    \
            float iv = sigmoid_f(ACC[0][r]);             \
            float fv = sigmoid_f(ACC[1][r]);             \
            float gv = fmaxf(ACC[2][r], 0.f);            \
            float ov = sigmoid_f(ACC[3][r]);             \
            float cc = fmaf(fv, cs[r], iv * gv);         \
            cs[r] = cc;                                  \
            hv[r] = ov * fmaxf(cc, 0.f);                 \
        }                                                \
        OWN.x = pk(hv[0], hv[1]);                        \
        OWN.y = pk(hv[2], hv[3]);                        \
    }

    // ------------------------- role-specific weight staging -------------------------
    if (con) {
#pragma unroll
        for (int q = 0; q < 4; ++q) {
            const int n = 2 * q + rw;
#pragma unroll
            for (int i = 0; i < 8; ++i)
                ueF[q][i] = (short)bfb(Ue[(4 * g + (i & 3) + 16 * (i >> 2)) * G_ + 16 * n + c]);
        }
    } else {
#pragma unroll
        for (int q = 0; q < 4; ++q) {
            const int n = 2 * q + rw;
#pragma unroll
            for (int kc = 0; kc < 2; ++kc)
#pragma unroll
                for (int i = 0; i < 8; ++i)
                    weF[q][kc][i] = (short)bfb(We[(kc * 32 + 8 * g + i) * G_ + 16 * n + c]);
            beC[q] = *(const f32x4*)(be + 16 * n + 4 * g);
        }
        // prologue: zx[0] into buf 0, then stage x[1]
        xa = *(const f32x4*)(xr + xo);
        xb = *(const f32x4*)(xr + xo + 4);
        xc = *(const f32x4*)(xr + 32 + xo);
        xd = *(const f32x4*)(xr + 36 + xo);
        short8 xf0, xf1;
        CVTX(xf0, xf1)
#pragma unroll
        for (int q = 0; q < 4; ++q) {
            f32x4 z = MFMA16(weF[q][0], xf0, beC[q]);
            z = MFMA16(weF[q][1], xf1, z);
            zxbuf[0][2 * q + rw][lane] = z;
        }
        const float* xn = xr + F_;
        xa = *(const f32x4*)(xn + xo);
        xb = *(const f32x4*)(xn + xo + 4);
        xc = *(const f32x4*)(xn + 32 + xo);
        xd = *(const f32x4*)(xn + 36 + xo);
    }
    __syncthreads();
    if (con) {
#pragma unroll
        for (int q = 0; q < 4; ++q) zxC[q] = zxbuf[0][2 * q + rw][lane];
    }

    // ================================ encoder scan ================================
#pragma unroll 1
    for (int t = 0; t < T_; ++t) {
        uint2v own;
        if (con) {
            f32x4 acc[4];
#pragma unroll
            for (int q = 0; q < 4; ++q)
                acc[q] = MFMA16(ueF[q], hfrag, zxC[q]);   // z = zx + Ue^T h (1 dep MFMA)
            GATES4(acc, own)
            *(uint2v*)&hx[t & 1][c * 18 + 8 * rw + 2 * g] = own;
        } else if (t + 1 < T_) {
            short8 xf0, xf1;
            CVTX(xf0, xf1)
            if (t + 2 < T_) {   // stage x[t+2] (cvt above already consumed old regs)
                const float* xn = xr + (t + 2) * F_;
                xa = *(const f32x4*)(xn + xo);
                xb = *(const f32x4*)(xn + xo + 4);
                xc = *(const f32x4*)(xn + 32 + xo);
                xd = *(const f32x4*)(xn + 36 + xo);
            }
#pragma unroll
            for (int q = 0; q < 4; ++q) {
                f32x4 z = MFMA16(weF[q][0], xf0, beC[q]);
                z = MFMA16(weF[q][1], xf1, z);
                zxbuf[(t + 1) & 1][2 * q + rw][lane] = z;
            }
        }
        __syncthreads();
        if (con) {
            uint2v oth = *(const uint2v*)&hx[t & 1][c * 18 + 8 * (1 - rw) + 2 * g];
            uint4v hb;
            hb.x = rw ? oth.x : own.x;   // elems 0-3: hidden 4g+r (wave-0 half)
            hb.y = rw ? oth.y : own.y;
            hb.z = rw ? own.x : oth.x;   // elems 4-7: hidden 16+4g+r (wave-1 half)
            hb.w = rw ? own.y : oth.y;
            hfrag = __builtin_bit_cast(short8, hb);
            if (t + 1 < T_) {
#pragma unroll
                for (int q = 0; q < 4; ++q)
                    zxC[q] = zxbuf[(t + 1) & 1][2 * q + rw][lane];  // prefetch next C
            }
        }
    }

    // ------------------ transition: decoder weights (no barrier needed) ------------------
    short8 udF[4];
    f32x4  zd[4];
    short8 woF[2];
    f32x4  boC[2];
    float* ob[4];
    if (con) {
        short8 wdF[4];
#pragma unroll
        for (int q = 0; q < 4; ++q) {
            const int n = 2 * q + rw;
#pragma unroll
            for (int i = 0; i < 8; ++i) {
                const int pr = 4 * g + (i & 3) + 16 * (i >> 2);
                wdF[q][i] = (short)bfb(Wd[pr * G_ + 16 * n + c]);
                udF[q][i] = (short)bfb(Ud[pr * G_ + 16 * n + c]);
            }
        }
#pragma unroll
        for (int q = 0; q < 4; ++q) {
            f32x4 tb = *(const f32x4*)(bd + 16 * (2 * q + rw) + 4 * g);
            zd[q] = MFMA16(wdF[q], hfrag, tb);   // hfrag == full hT here
        }
        hfrag = (short8)0;
#pragma unroll
        for (int r = 0; r < 4; ++r) cs[r] = 0.f;
    } else {
#pragma unroll
        for (int mi = 0; mi < 2; ++mi) {
            const int m = 2 * rw + mi;
#pragma unroll
            for (int i = 0; i < 8; ++i)
                woF[mi][i] = (short)bfb(Wout[(4 * g + (i & 3) + 16 * (i >> 2)) * F_ + 16 * m + c]);
            float v = bout[16 * m + c];
            boC[mi][0] = v; boC[mi][1] = v; boC[mi][2] = v; boC[mi][3] = v;
        }
#pragma unroll
        for (int r = 0; r < 4; ++r)
            ob[r] = out + (size_t)(b0 + 4 * g + r) * (T_ * F_) + c;
    }

    // ==================== decoder scan; helpers do the out-projection ====================
#pragma unroll 1
    for (int t = 0; t < T_; ++t) {
        uint2v own;
        if (con) {
            f32x4 acc[4];
#pragma unroll
            for (int q = 0; q < 4; ++q)
                acc[q] = MFMA16(udF[q], hfrag, zd[q]);   // z = zd + Ud^T h
            GATES4(acc, own)
            *(uint2v*)&hx[t & 1][c * 18 + 8 * rw + 2 * g] = own;
        }
        __syncthreads();
        if (con) {
            uint2v oth = *(const uint2v*)&hx[t & 1][c * 18 + 8 * (1 - rw) + 2 * g];
            uint4v hb;
            hb.x = rw ? oth.x : own.x;
            hb.y = rw ? oth.y : own.y;
            hb.z = rw ? own.x : oth.x;
            hb.w = rw ? own.y : oth.y;
            hfrag = __builtin_bit_cast(short8, hb);
        } else {
            // h_t as A-frag (rows = batch c, k = p(g,i)): read both halves from hx.
            // Safe: consumers re-write this hx parity only after the NEXT barrier.
            uint2v ha = *(const uint2v*)&hx[t & 1][c * 18 + 2 * g];
            uint2v hz = *(const uint2v*)&hx[t & 1][c * 18 + 8 + 2 * g];
            uint4v u; u.x = ha.x; u.y = ha.y; u.z = hz.x; u.w = hz.y;
            short8 hA = __builtin_bit_cast(short8, u);
#pragma unroll
            for (int mi = 0; mi < 2; ++mi) {
                f32x4 oac = MFMA16(hA, woF[mi], boC[mi]);
                const int m = 2 * rw + mi;
#pragma unroll
                for (int r = 0; r < 4; ++r)
                    ob[r][t * F_ + 16 * m] = oac[r];
            }
        }
    }
}

extern "C" void kernel_launch(void* const* d_in, const int* in_sizes, int n_in,
                              void* d_out, int out_size, void* d_ws, size_t ws_size,
                              hipStream_t stream) {
    (void)in_sizes; (void)n_in; (void)d_ws; (void)ws_size; (void)out_size;
    const float* x    = (const float*)d_in[0];
    const float* We   = (const float*)d_in[1];
    const float* Ue   = (const float*)d_in[2];
    const float* be   = (const float*)d_in[3];
    const float* Wd   = (const float*)d_in[4];
    const float* Ud   = (const float*)d_in[5];
    const float* bd   = (const float*)d_in[6];
    const float* Wout = (const float*)d_in[7];
    const float* bout = (const float*)d_in[8];
    float* out = (float*)d_out;

    dim3 grid(B_ / 16), block(256);
    hipLaunchKernelGGL(lstm_ae, grid, block, 0, stream,
                       x, We, Ue, be, Wd, Ud, bd, Wout, bout, out);
}